// Round 1
// baseline (72.036 us; speedup 1.0000x reference)
//
#include <hip/hip_runtime.h>
#include <hip/hip_bf16.h>
#include <math.h>

// One thread per 8x8 DLT system. Build augmented [A|b] in fp64 with the
// reference's trunc() semantics, Gaussian-eliminate with partial pivoting
// (conditional-swap form: all indexing static so arrays live in VGPRs),
// back-substitute, emit h0..h7, 1.0 as float32.
__global__ __launch_bounds__(256) void TensorDlt_48215302865189_kernel(
    const float* __restrict__ x, const float* __restrict__ xp,
    float* __restrict__ out, int B) {
  int i = blockIdx.x * blockDim.x + threadIdx.x;
  if (i >= B) return;

  // x row: [u0,v0,u1,v1,u2,v2,u3,v3]; xp row: [up0,vp0,...]
  const float4* x4 = reinterpret_cast<const float4*>(x + (size_t)i * 8);
  float4 a0 = x4[0], a1 = x4[1];
  const float4* p4 = reinterpret_cast<const float4*>(xp + (size_t)i * 8);
  float4 c0 = p4[0], c1 = p4[1];

  double u[4]  = {a0.x, a0.z, a1.x, a1.z};
  double v[4]  = {a0.y, a0.w, a1.y, a1.w};
  double up[4] = {c0.x, c0.z, c1.x, c1.z};
  double vp[4] = {c0.y, c0.w, c1.y, c1.w};

  double A[8][9];  // augmented [A | b]
#pragma unroll
  for (int k = 0; k < 4; k++) {
    double U = trunc(u[k]), V = trunc(v[k]);
    double W = trunc(vp[k] * u[k]), X = trunc(vp[k] * v[k]);
    double Y = trunc(up[k] * u[k]), Z = trunc(up[k] * v[k]);
    // x-row (row 2k):  [0,0,0,-U,-V,-1, W, X | -vp]
    A[2 * k][0] = 0.0;  A[2 * k][1] = 0.0;  A[2 * k][2] = 0.0;
    A[2 * k][3] = -U;   A[2 * k][4] = -V;   A[2 * k][5] = -1.0;
    A[2 * k][6] = W;    A[2 * k][7] = X;    A[2 * k][8] = -vp[k];
    // y-row (row 2k+1): [U,V,1, 0,0,0, -Y,-Z | up]
    A[2 * k + 1][0] = U;   A[2 * k + 1][1] = V;   A[2 * k + 1][2] = 1.0;
    A[2 * k + 1][3] = 0.0; A[2 * k + 1][4] = 0.0; A[2 * k + 1][5] = 0.0;
    A[2 * k + 1][6] = -Y;  A[2 * k + 1][7] = -Z;  A[2 * k + 1][8] = up[k];
  }

  // Gaussian elimination with partial pivoting. Pivot selection is done by
  // bubbling the max-|A[r][k]| row into row k via unrolled conditional swaps,
  // keeping every index a compile-time constant (no scratch).
#pragma unroll
  for (int k = 0; k < 8; k++) {
#pragma unroll
    for (int r = k + 1; r < 8; r++) {
      bool sw = fabs(A[r][k]) > fabs(A[k][k]);
#pragma unroll
      for (int c = k; c < 9; c++) {
        double t0 = A[k][c], t1 = A[r][c];
        A[k][c] = sw ? t1 : t0;
        A[r][c] = sw ? t0 : t1;
      }
    }
    double pinv = 1.0 / A[k][k];
#pragma unroll
    for (int r = k + 1; r < 8; r++) {
      double f = A[r][k] * pinv;
#pragma unroll
      for (int c = k + 1; c < 9; c++) A[r][c] -= f * A[k][c];
    }
  }

  // Back substitution.
  double h[8];
#pragma unroll
  for (int k = 7; k >= 0; k--) {
    double s = A[k][8];
#pragma unroll
    for (int c = k + 1; c < 8; c++) s -= A[k][c] * h[c];
    h[k] = s / A[k][k];
  }

  float* o = out + (size_t)i * 9;
#pragma unroll
  for (int k = 0; k < 8; k++) o[k] = (float)h[k];
  o[8] = 1.0f;
}

extern "C" void kernel_launch(void* const* d_in, const int* in_sizes, int n_in,
                              void* d_out, int out_size, void* d_ws, size_t ws_size,
                              hipStream_t stream) {
  const float* x  = (const float*)d_in[0];
  const float* xp = (const float*)d_in[1];
  float* out = (float*)d_out;
  int B = in_sizes[0] / 8;  // 262144
  int block = 256;
  int grid = (B + block - 1) / block;
  TensorDlt_48215302865189_kernel<<<grid, block, 0, stream>>>(x, xp, out, B);
}

// Round 3
// 67.073 us; speedup vs baseline: 1.0740x; 1.0740x over previous
//
#include <hip/hip_runtime.h>
#include <hip/hip_bf16.h>
#include <math.h>

// One thread per 8x8 DLT system, exploiting the block structure:
//   y-row k:  U_k h0 + V_k h1 + h2           - Y_k h6 - Z_k h7 = up_k
//   x-row k:            U_k h3 + V_k h4 + h5 - W_k h6 - X_k h7 = vp_k
// with U=trunc(u), V=trunc(v), Y=trunc(up*u), Z=trunc(up*v),
//      W=trunc(vp*u), X=trunc(vp*v)  (reference's .long() truncation).
//
// R2 failed with NaN: pivoting unconditionally on points {0,1,2} divides by
// det(M3)==0 when that truncated triple is exactly collinear (integer coords,
// P~2e-5/system -> ~5 hits in 262144). Fix: evaluate all four point-triples,
// keep the one with max |det| (provably nonzero whenever the full 8x8 A is
// invertible), permute points so it sits in slots 0..2. All indexing static
// -> everything stays in VGPRs.
__global__ __launch_bounds__(256) void TensorDlt_48215302865189_kernel(
    const float* __restrict__ x, const float* __restrict__ xp,
    float* __restrict__ out, int B) {
  int i = blockIdx.x * blockDim.x + threadIdx.x;
  if (i >= B) return;

  const float4* x4 = reinterpret_cast<const float4*>(x + (size_t)i * 8);
  float4 a0 = x4[0], a1 = x4[1];
  const float4* p4 = reinterpret_cast<const float4*>(xp + (size_t)i * 8);
  float4 c0 = p4[0], c1 = p4[1];

  double u[4]  = {a0.x, a0.z, a1.x, a1.z};
  double v[4]  = {a0.y, a0.w, a1.y, a1.w};
  double up[4] = {c0.x, c0.z, c1.x, c1.z};
  double vp[4] = {c0.y, c0.w, c1.y, c1.w};

  double U[4], V[4], Y[4], Z[4], W[4], X[4];
#pragma unroll
  for (int k = 0; k < 4; k++) {
    U[k] = trunc(u[k]);
    V[k] = trunc(v[k]);
    Y[k] = trunc(up[k] * u[k]);
    Z[k] = trunc(up[k] * v[k]);
    W[k] = trunc(vp[k] * u[k]);
    X[k] = trunc(vp[k] * v[k]);
  }

  // Signed dets of the four point-triples; de excludes point e.
  double d3 = U[0] * (V[1] - V[2]) + U[1] * (V[2] - V[0]) + U[2] * (V[0] - V[1]);
  double d2 = U[0] * (V[1] - V[3]) + U[1] * (V[3] - V[0]) + U[3] * (V[0] - V[1]);
  double d1 = U[0] * (V[2] - V[3]) + U[2] * (V[3] - V[0]) + U[3] * (V[0] - V[2]);
  double d0 = U[1] * (V[2] - V[3]) + U[2] * (V[3] - V[1]) + U[3] * (V[1] - V[2]);

  int e = 3;
  double bd = fabs(d3);
  if (fabs(d2) > bd) { e = 2; bd = fabs(d2); }
  if (fabs(d1) > bd) { e = 1; bd = fabs(d1); }
  if (fabs(d0) > bd) { e = 0; bd = fabs(d0); }

  // Permute points so excluded point e lands in slot 3, kept triple in 0..2.
  // slot0 <- (e==0 ? 1 : 0); slot1 <- (e>=2 ? 1 : 2);
  // slot2 <- (e==3 ? 2 : 3); slot3 <- e.
#define PERM4(a)                                                             \
  {                                                                          \
    double p0 = (e == 0) ? a[1] : a[0];                                      \
    double p1 = (e >= 2) ? a[1] : a[2];                                      \
    double p2 = (e == 3) ? a[2] : a[3];                                      \
    double p3 = (e == 3) ? a[3] : (e == 2) ? a[2] : (e == 1) ? a[1] : a[0];  \
    a[0] = p0; a[1] = p1; a[2] = p2; a[3] = p3;                              \
  }
  PERM4(U); PERM4(V); PERM4(Y); PERM4(Z); PERM4(W); PERM4(X);
  PERM4(up); PERM4(vp);
#undef PERM4

  // Adjugate + det of M3 = [[U0,V0,1],[U1,V1,1],[U2,V2,1]] (permuted slots).
  double N00 = V[1] - V[2], N01 = V[2] - V[0], N02 = V[0] - V[1];
  double N10 = U[2] - U[1], N11 = U[0] - U[2], N12 = U[1] - U[0];
  double N20 = U[1] * V[2] - V[1] * U[2];
  double N21 = U[2] * V[0] - V[2] * U[0];
  double N22 = U[0] * V[1] - V[0] * U[1];
  double det = U[0] * N00 + V[0] * N10 + N20;

  // q = (U3, V3, 1) * N  (scaled row-3 elimination weights).
  double q0 = U[3] * N00 + V[3] * N10 + N20;
  double q1 = U[3] * N01 + V[3] * N11 + N21;
  double q2 = U[3] * N02 + V[3] * N12 + N22;

  // Reduced 2x2 in (h6, h7).
  double A1 = q0 * Y[0] + q1 * Y[1] + q2 * Y[2] - det * Y[3];
  double B1 = q0 * Z[0] + q1 * Z[1] + q2 * Z[2] - det * Z[3];
  double R1 = det * up[3] - (q0 * up[0] + q1 * up[1] + q2 * up[2]);
  double A2 = q0 * W[0] + q1 * W[1] + q2 * W[2] - det * W[3];
  double B2 = q0 * X[0] + q1 * X[1] + q2 * X[2] - det * X[3];
  double R2 = det * vp[3] - (q0 * vp[0] + q1 * vp[1] + q2 * vp[2]);

  double D2inv = 1.0 / (A1 * B2 - A2 * B1);
  double h6 = (R1 * B2 - R2 * B1) * D2inv;
  double h7 = (A1 * R2 - A2 * R1) * D2inv;

  // Back-substitution: M3 g1 = up + Cy g3, M3 g2 = vp + Cx g3.
  double detinv = 1.0 / det;
  double r0 = up[0] + Y[0] * h6 + Z[0] * h7;
  double r1 = up[1] + Y[1] * h6 + Z[1] * h7;
  double r2 = up[2] + Y[2] * h6 + Z[2] * h7;
  double h0 = (N00 * r0 + N01 * r1 + N02 * r2) * detinv;
  double h1 = (N10 * r0 + N11 * r1 + N12 * r2) * detinv;
  double h2 = (N20 * r0 + N21 * r1 + N22 * r2) * detinv;

  double s0 = vp[0] + W[0] * h6 + X[0] * h7;
  double s1 = vp[1] + W[1] * h6 + X[1] * h7;
  double s2 = vp[2] + W[2] * h6 + X[2] * h7;
  double h3 = (N00 * s0 + N01 * s1 + N02 * s2) * detinv;
  double h4 = (N10 * s0 + N11 * s1 + N12 * s2) * detinv;
  double h5 = (N20 * s0 + N21 * s1 + N22 * s2) * detinv;

  float* o = out + (size_t)i * 9;
  o[0] = (float)h0; o[1] = (float)h1; o[2] = (float)h2;
  o[3] = (float)h3; o[4] = (float)h4; o[5] = (float)h5;
  o[6] = (float)h6; o[7] = (float)h7; o[8] = 1.0f;
}

extern "C" void kernel_launch(void* const* d_in, const int* in_sizes, int n_in,
                              void* d_out, int out_size, void* d_ws, size_t ws_size,
                              hipStream_t stream) {
  const float* x  = (const float*)d_in[0];
  const float* xp = (const float*)d_in[1];
  float* out = (float*)d_out;
  int B = in_sizes[0] / 8;  // 262144
  int block = 256;
  int grid = (B + block - 1) / block;
  TensorDlt_48215302865189_kernel<<<grid, block, 0, stream>>>(x, xp, out, B);
}